// Round 17
// baseline (63.133 us; speedup 1.0000x reference)
//
#include <hip/hip_runtime.h>
#include <hip/hip_bf16.h>

#define N_SOURCE   100000
#define N_TARGET   4096
#define SOURCE_DIM 512
#define EMBED_DIM  32
#define TARGET_DIM 16
#define NTILES     ((N_SOURCE + 15) / 16)   // 6250 row-tiles of 16 (exact)

typedef __attribute__((ext_vector_type(8))) short short8;   // 8 bf16 (4 VGPR)
typedef __attribute__((ext_vector_type(4))) float f32x4;    // MFMA accumulator

static __device__ __forceinline__ ushort f2bf(float f) {
    __hip_bfloat16 h = __float2bfloat16(f);   // RNE
    return *(ushort*)&h;
}

// ---------------------------------------------------------------------------
// Kernel 0: Mt = bf16( (embed @ weight)^T )   [16][512]  (folds both GEMMs)
// ---------------------------------------------------------------------------
__global__ __launch_bounds__(256)
void k_embed_weight(const float* __restrict__ embed,   // [512][32]
                    const float* __restrict__ weight,  // [32][16]
                    ushort* __restrict__ Mt) {         // [16][512] bf16
    __shared__ float wlds[EMBED_DIM * TARGET_DIM];
    int tid = threadIdx.x;
    for (int i = tid; i < EMBED_DIM * TARGET_DIM; i += 256)
        wlds[i] = weight[i];
    __syncthreads();

    int idx = blockIdx.x * 256 + tid;                  // 0..8191
    if (idx < SOURCE_DIM * TARGET_DIM) {
        int k = idx >> 4;        // K index
        int o = idx & 15;        // output col
        float s = 0.f;
        #pragma unroll
        for (int j = 0; j < EMBED_DIM; ++j)
            s += embed[k * EMBED_DIM + j] * wlds[j * TARGET_DIM + o];
        Mt[o * SOURCE_DIM + k] = f2bf(s);              // transposed store
    }
}

// ---------------------------------------------------------------------------
// Kernel 1: y = bf16( (A @ M) / xnorm ) via MFMA. R16 copy-shaped base.
// NEW vs R16: SPLIT-K STAGING. A-LDS halved to 8KB/wave (one K-half),
// reused for both halves:
//   load h0 -> write h0 -> barrier -> ISSUE h1 loads -> compute kk0-7
//   -> write h1 (same-wave WAR, lgkmcnt-ordered, no barrier) -> compute kk8-15
// Effects: LDS 80->48KB => 3 blocks/CU (24 waves, +50%); h1's 16 loads fly
// under the kk0-7 MFMA phase instead of serializing before the barrier.
// (R10's "occupancy flat" was measured under the scattered-line shape; with
// the copy shape, concurrency is the remaining untested constraint.)
// Swizzle unchanged: kkLocal = kk-8 has same parity as kk.
// ---------------------------------------------------------------------------
__global__ __launch_bounds__(256, 3)
void k_gemm_y(const float*  __restrict__ A,      // source_feat [N_SOURCE][512]
              const float*  __restrict__ xnorm,  // [N_SOURCE]
              const ushort* __restrict__ Mt,     // [16][512] bf16
              ushort*       __restrict__ y) {    // [N_SOURCE][16] bf16
    extern __shared__ ushort smem[];             // 48 KB dynamic
    ushort* Bl  = smem;                          // 8192 ushorts = 16 KB
    int tid  = threadIdx.x;
    int wave = tid >> 6;
    int lane = tid & 63;
    ushort* AlW = smem + 8192 + wave * 4096;     // this wave's 8 KB half-buffer

    // ---- stage B in fragment order (R8-proven, conflict-free) ----
    #pragma unroll
    for (int i = 0; i < 4; ++i) {
        int c  = tid + 256 * i;          // 0..1023
        int nn = c & 15;
        int kg = c >> 4;                 // kk*4+g
        int kk = kg >> 2;
        int gg = kg & 3;
        *(uint4*)&Bl[c * 8] =
            *(const uint4*)(Mt + nn * SOURCE_DIM + kk * 32 + gg * 8);
    }

    int tile  = blockIdx.x * 4 + wave;
    int tilec = tile < NTILES ? tile : NTILES - 1;   // clamp addrs only
    int row0  = tilec * 16;

    // writer constants: logical(half) = (l>>3)*1024 + ((l>>1)&3)*256
    //                                 + r*16 + (l&1)*8 ; swz ^= ((log>>8)&7)<<4
    int laneConst = ((lane >> 3) << 10) | (((lane >> 1) & 3) << 8) | ((lane & 1) << 3);
    int xl        = (laneConst >> 8) & 7;

    // ---- load half 0 (16 copy-shaped loads: 1KB contiguous / instr) ----
    f32x4 v0[16];
    #pragma unroll
    for (int r = 0; r < 16; ++r)
        v0[r] = *(const f32x4*)(A + (size_t)(row0 + r) * SOURCE_DIM + lane * 4);

    // ---- write half 0 into swizzled wave-private LDS ----
    #pragma unroll
    for (int r = 0; r < 16; ++r) {
        uint d0 = (uint)f2bf(v0[r][0]) | ((uint)f2bf(v0[r][1]) << 16);
        uint d1 = (uint)f2bf(v0[r][2]) | ((uint)f2bf(v0[r][3]) << 16);
        *(uint2*)((char*)AlW + laneConst + ((r ^ xl) << 4)) = make_uint2(d0, d1);
    }

    __syncthreads();   // Bl visible; drains only h0 (already consumed)

    // ---- issue half-1 loads: in flight under the kk0-7 compute ----
    f32x4 v1[16];
    #pragma unroll
    for (int r = 0; r < 16; ++r)
        v1[r] = *(const f32x4*)(A + (size_t)(row0 + r) * SOURCE_DIM + 256 + lane * 4);

    int n = lane & 15;     // C col
    int g = lane >> 4;     // k-group 0..3
    const ushort* Bll = Bl + lane * 8;       // +kk*512 ushorts per step

    f32x4 acc = {0.f, 0.f, 0.f, 0.f};

    // ---- compute kk = 0..7 from the half-buffer ----
    #pragma unroll
    for (int kk = 0; kk < 8; ++kk) {
        int xr = (4 * kk + (lane >> 4)) & 7;
        const short8 af = *(const short8*)
            ((char*)AlW + kk * 1024 + ((lane ^ xr) << 4));
        const short8 bf = *(const short8*)(Bll + kk * 512);
        acc = __builtin_amdgcn_mfma_f32_16x16x32_bf16(af, bf, acc, 0, 0, 0);
    }

    // ---- write half 1 (WAR on h0 reads; same-wave ds ordering) ----
    #pragma unroll
    for (int r = 0; r < 16; ++r) {
        uint d0 = (uint)f2bf(v1[r][0]) | ((uint)f2bf(v1[r][1]) << 16);
        uint d1 = (uint)f2bf(v1[r][2]) | ((uint)f2bf(v1[r][3]) << 16);
        *(uint2*)((char*)AlW + laneConst + ((r ^ xl) << 4)) = make_uint2(d0, d1);
    }

    // ---- compute kk = 8..15 ----
    #pragma unroll
    for (int kk = 8; kk < 16; ++kk) {
        int kl = kk - 8;                       // same parity as kk
        int xr = (4 * kl + (lane >> 4)) & 7;
        const short8 af = *(const short8*)
            ((char*)AlW + kl * 1024 + ((lane ^ xr) << 4));
        const short8 bf = *(const short8*)(Bll + kk * 512);
        acc = __builtin_amdgcn_mfma_f32_16x16x32_bf16(af, bf, acc, 0, 0, 0);
    }

    if (tile < NTILES) {
        // epilogue: lane holds C[g*4 + r][n], r = 0..3
        int m0 = g * 4;
        float4 xn = *(const float4*)(xnorm + row0 + m0);   // 16B aligned
        const float xr4[4] = {xn.x, xn.y, xn.z, xn.w};
        #pragma unroll
        for (int r = 0; r < 4; ++r)
            y[(size_t)(row0 + m0 + r) * TARGET_DIM + n] = f2bf(acc[r] / xr4[r]);
    }
}

// ---------------------------------------------------------------------------
// Kernel 2 (exact round-6/8 version, measured 14.7 us): block per target,
// int4 index loads -> 4 independent uint4 gathers (ILP 4).
// ---------------------------------------------------------------------------
__global__ __launch_bounds__(256)
void k_gather_mean(const ushort* __restrict__ y,   // [N_SOURCE][16] bf16
                   const int*    __restrict__ src, // edge sources
                   const int*    __restrict__ rl,  // range_list [N_TARGET][2]
                   float* __restrict__ out) {      // [N_TARGET][16] f32
    int t     = blockIdx.x;
    int tid   = threadIdx.x;
    int start = rl[2 * t];
    int end   = rl[2 * t + 1];

    int slot = tid >> 1;          // 0..127
    int sub  = tid & 1;           // which 16B half of the 32B row

    float a[8];
    #pragma unroll
    for (int i = 0; i < 8; ++i) a[i] = 0.f;

    for (int base = start + slot * 4; base < end; base += 512) {
        int rem = end - base;     // >= 1 here
        int id[4];
        if (rem >= 4) {           // aligned: start%4==0 (range starts 800*t)
            int4 qd = *(const int4*)(src + base);
            id[0] = qd.x; id[1] = qd.y; id[2] = qd.z; id[3] = qd.w;
        } else {
            #pragma unroll
            for (int j = 0; j < 4; ++j) id[j] = (j < rem) ? src[base + j] : 0;
        }
        #pragma unroll
        for (int j = 0; j < 4; ++j) {
            if (j < rem) {
                uint4 v = *(const uint4*)(y + (size_t)id[j] * TARGET_DIM + sub * 8);
                const uint w[4] = {v.x, v.y, v.z, v.w};
                #pragma unroll
                for (int i = 0; i < 4; ++i) {
                    uint lo = w[i] << 16;
                    uint hiw = w[i] & 0xffff0000u;
                    a[2 * i]     += *(float*)&lo;
                    a[2 * i + 1] += *(float*)&hiw;
                }
            }
        }
    }

    // butterfly over slot bits within the wave (lane bits 1..5)
    #pragma unroll
    for (int m = 2; m <= 32; m <<= 1) {
        #pragma unroll
        for (int i = 0; i < 8; ++i) a[i] += __shfl_xor(a[i], m);
    }

    __shared__ float red[4][16];
    int wid  = tid >> 6;
    int lane = tid & 63;
    if (lane < 2) {               // lane0 = cols 0..7, lane1 = cols 8..15
        #pragma unroll
        for (int i = 0; i < 8; ++i) red[wid][lane * 8 + i] = a[i];
    }
    __syncthreads();

    if (tid < TARGET_DIM) {
        float s = red[0][tid] + red[1][tid] + red[2][tid] + red[3][tid];
        float deg = (float)(end - start);
        deg = deg > 1.f ? deg : 1.f;
        out[t * TARGET_DIM + tid] = s / deg;
    }
}

// ---------------------------------------------------------------------------
extern "C" void kernel_launch(void* const* d_in, const int* in_sizes, int n_in,
                              void* d_out, int out_size, void* d_ws, size_t ws_size,
                              hipStream_t stream) {
    const float* source_feat = (const float*)d_in[0];  // [100000][512]
    const float* embed       = (const float*)d_in[1];  // [512][32]
    const float* weight      = (const float*)d_in[2];  // [32][16]
    const int*   edge_src    = (const int*)d_in[3];    // edge_index[0][:]
    const int*   range_list  = (const int*)d_in[4];    // [4096][2]
    const float* x_norm      = (const float*)d_in[5];  // [100000]

    float*  out = (float*)d_out;
    ushort* Mt  = (ushort*)d_ws;                        // 16 KB bf16 [16][512]
    ushort* y   = (ushort*)((char*)d_ws + 16384);       // 3.2 MB bf16

    k_embed_weight<<<32, 256, 0, stream>>>(embed, weight, Mt);

    int nblk = (NTILES + 3) / 4;                        // 1563
    k_gemm_y<<<nblk, 256, 49152, stream>>>(source_feat, x_norm, Mt, y);

    k_gather_mean<<<N_TARGET, 256, 0, stream>>>(y, edge_src, range_list, out);
}

// Round 18
// 61.633 us; speedup vs baseline: 1.0243x; 1.0243x over previous
//
#include <hip/hip_runtime.h>
#include <hip/hip_bf16.h>

#define N_SOURCE   100000
#define N_TARGET   4096
#define SOURCE_DIM 512
#define EMBED_DIM  32
#define TARGET_DIM 16
#define NTILES     ((N_SOURCE + 15) / 16)   // 6250 row-tiles of 16 (exact)

typedef __attribute__((ext_vector_type(8))) short short8;   // 8 bf16 (4 VGPR)
typedef __attribute__((ext_vector_type(4))) float f32x4;    // MFMA accumulator

static __device__ __forceinline__ ushort f2bf(float f) {
    __hip_bfloat16 h = __float2bfloat16(f);   // RNE
    return *(ushort*)&h;
}

// ---------------------------------------------------------------------------
// Kernel 0: Mt = bf16( (embed @ weight)^T )   [16][512]  (folds both GEMMs)
// ---------------------------------------------------------------------------
__global__ __launch_bounds__(256)
void k_embed_weight(const float* __restrict__ embed,   // [512][32]
                    const float* __restrict__ weight,  // [32][16]
                    ushort* __restrict__ Mt) {         // [16][512] bf16
    __shared__ float wlds[EMBED_DIM * TARGET_DIM];
    int tid = threadIdx.x;
    for (int i = tid; i < EMBED_DIM * TARGET_DIM; i += 256)
        wlds[i] = weight[i];
    __syncthreads();

    int idx = blockIdx.x * 256 + tid;                  // 0..8191
    if (idx < SOURCE_DIM * TARGET_DIM) {
        int k = idx >> 4;        // K index
        int o = idx & 15;        // output col
        float s = 0.f;
        #pragma unroll
        for (int j = 0; j < EMBED_DIM; ++j)
            s += embed[k * EMBED_DIM + j] * wlds[j * TARGET_DIM + o];
        Mt[o * SOURCE_DIM + k] = f2bf(s);              // transposed store
    }
}

// ---------------------------------------------------------------------------
// Kernel 1 (exact R16 version, best measured 61.5us total):
// y = bf16( (A @ M) / xnorm ) via MFMA, copy-shaped A loads.
// Load j (j=0..31): row j/2, half j&1 — 64 lanes read 1KB CONTIGUOUS
// (8 sequential 128B lines/instr, m13 copy shape). bf16-cvt + swizzled
// ds_write_b64 into per-wave fragment-ordered A-LDS; consume is
// ds_read_b128 (linear-in-lane, conflict-free) + MFMA — no shfl/cvt in
// the hot loop. Swizzle: phys = logical ^ (((logical>>8)&7)<<4).
// LDS: Bl 16KB + 4x16KB A = 80KB dynamic -> 2 blocks/CU.
// Knob scan closed (R9-R17): occupancy/depth/L3/nt/split-K all null or
// negative; line shape was the one win. 205MB @ 5.0 TB/s = 79% of copy
// ceiling with staging overhead.
// ---------------------------------------------------------------------------
__global__ __launch_bounds__(256, 2)
void k_gemm_y(const float*  __restrict__ A,      // source_feat [N_SOURCE][512]
              const float*  __restrict__ xnorm,  // [N_SOURCE]
              const ushort* __restrict__ Mt,     // [16][512] bf16
              ushort*       __restrict__ y) {    // [N_SOURCE][16] bf16
    extern __shared__ ushort smem[];             // 80 KB dynamic
    ushort* Bl  = smem;                          // 8192 ushorts = 16 KB
    int tid  = threadIdx.x;
    int wave = tid >> 6;
    int lane = tid & 63;
    ushort* AlW = smem + 8192 + wave * 8192;     // this wave's 16 KB A tile

    // ---- stage B in fragment order (R8-proven, conflict-free) ----
    #pragma unroll
    for (int i = 0; i < 4; ++i) {
        int c  = tid + 256 * i;          // 0..1023
        int nn = c & 15;
        int kg = c >> 4;                 // kk*4+g
        int kk = kg >> 2;
        int gg = kg & 3;
        *(uint4*)&Bl[c * 8] =
            *(const uint4*)(Mt + nn * SOURCE_DIM + kk * 32 + gg * 8);
    }

    // ---- stage A: 32 copy-shaped loads -> cvt -> swizzled ds_write_b64 ----
    int tile  = blockIdx.x * 4 + wave;
    int tilec = tile < NTILES ? tile : NTILES - 1;   // clamp addrs only
    int row0  = tilec * 16;

    // lane-constant parts of the write address:
    // logical = h*8192 + (l>>3)*1024 + ((l>>1)&3)*256 + r*16 + (l&1)*8
    // swizzle x = (4*(l>>3) + ((l>>1)&3)) & 7  (lane-const)
    int laneConst = ((lane >> 3) << 10) | (((lane >> 1) & 3) << 8) | ((lane & 1) << 3);
    int xl        = ((laneConst >> 8) & 7);

    #pragma unroll
    for (int j = 0; j < 32; ++j) {
        int r = j >> 1, h = j & 1;
        f32x4 v = *(const f32x4*)(A + (size_t)(row0 + r) * SOURCE_DIM
                                    + h * 256 + lane * 4);
        uint d0 = (uint)f2bf(v[0]) | ((uint)f2bf(v[1]) << 16);
        uint d1 = (uint)f2bf(v[2]) | ((uint)f2bf(v[3]) << 16);
        int phys = laneConst + (h << 13) + ((r ^ xl) << 4);
        *(uint2*)((char*)AlW + phys) = make_uint2(d0, d1);
    }

    __syncthreads();   // Bl visible (A writes are same-wave, covered anyway)

    if (tile < NTILES) {
        int n = lane & 15;     // C col / A row
        int g = lane >> 4;     // k-group 0..3
        const ushort* Bll = Bl + lane * 8;       // +kk*512 ushorts per step

        f32x4 acc = {0.f, 0.f, 0.f, 0.f};
        #pragma unroll
        for (int kk = 0; kk < 16; ++kk) {
            // A fragment: logical chunk = kk*64 + lane; swz lands on lane&7
            int xr = (4 * kk + (lane >> 4)) & 7;
            const short8 af = *(const short8*)
                ((char*)AlW + kk * 1024 + ((lane ^ xr) << 4));
            const short8 bf = *(const short8*)(Bll + kk * 512);
            acc = __builtin_amdgcn_mfma_f32_16x16x32_bf16(af, bf, acc, 0, 0, 0);
        }

        // epilogue: lane holds C[g*4 + r][n], r = 0..3
        int m0 = g * 4;
        float4 xn = *(const float4*)(xnorm + row0 + m0);   // 16B aligned
        const float xr4[4] = {xn.x, xn.y, xn.z, xn.w};
        #pragma unroll
        for (int r = 0; r < 4; ++r)
            y[(size_t)(row0 + m0 + r) * TARGET_DIM + n] = f2bf(acc[r] / xr4[r]);
    }
}

// ---------------------------------------------------------------------------
// Kernel 2 (exact round-6/8 version, measured 14.7 us): block per target,
// int4 index loads -> 4 independent uint4 gathers (ILP 4). Request-rate
// floor ~11us (6.55M uint4 requests, 2/edge = HW minimum for 32B rows).
// ---------------------------------------------------------------------------
__global__ __launch_bounds__(256)
void k_gather_mean(const ushort* __restrict__ y,   // [N_SOURCE][16] bf16
                   const int*    __restrict__ src, // edge sources
                   const int*    __restrict__ rl,  // range_list [N_TARGET][2]
                   float* __restrict__ out) {      // [N_TARGET][16] f32
    int t     = blockIdx.x;
    int tid   = threadIdx.x;
    int start = rl[2 * t];
    int end   = rl[2 * t + 1];

    int slot = tid >> 1;          // 0..127
    int sub  = tid & 1;           // which 16B half of the 32B row

    float a[8];
    #pragma unroll
    for (int i = 0; i < 8; ++i) a[i] = 0.f;

    for (int base = start + slot * 4; base < end; base += 512) {
        int rem = end - base;     // >= 1 here
        int id[4];
        if (rem >= 4) {           // aligned: start%4==0 (range starts 800*t)
            int4 qd = *(const int4*)(src + base);
            id[0] = qd.x; id[1] = qd.y; id[2] = qd.z; id[3] = qd.w;
        } else {
            #pragma unroll
            for (int j = 0; j < 4; ++j) id[j] = (j < rem) ? src[base + j] : 0;
        }
        #pragma unroll
        for (int j = 0; j < 4; ++j) {
            if (j < rem) {
                uint4 v = *(const uint4*)(y + (size_t)id[j] * TARGET_DIM + sub * 8);
                const uint w[4] = {v.x, v.y, v.z, v.w};
                #pragma unroll
                for (int i = 0; i < 4; ++i) {
                    uint lo = w[i] << 16;
                    uint hiw = w[i] & 0xffff0000u;
                    a[2 * i]     += *(float*)&lo;
                    a[2 * i + 1] += *(float*)&hiw;
                }
            }
        }
    }

    // butterfly over slot bits within the wave (lane bits 1..5)
    #pragma unroll
    for (int m = 2; m <= 32; m <<= 1) {
        #pragma unroll
        for (int i = 0; i < 8; ++i) a[i] += __shfl_xor(a[i], m);
    }

    __shared__ float red[4][16];
    int wid  = tid >> 6;
    int lane = tid & 63;
    if (lane < 2) {               // lane0 = cols 0..7, lane1 = cols 8..15
        #pragma unroll
        for (int i = 0; i < 8; ++i) red[wid][lane * 8 + i] = a[i];
    }
    __syncthreads();

    if (tid < TARGET_DIM) {
        float s = red[0][tid] + red[1][tid] + red[2][tid] + red[3][tid];
        float deg = (float)(end - start);
        deg = deg > 1.f ? deg : 1.f;
        out[t * TARGET_DIM + tid] = s / deg;
    }
}

// ---------------------------------------------------------------------------
extern "C" void kernel_launch(void* const* d_in, const int* in_sizes, int n_in,
                              void* d_out, int out_size, void* d_ws, size_t ws_size,
                              hipStream_t stream) {
    const float* source_feat = (const float*)d_in[0];  // [100000][512]
    const float* embed       = (const float*)d_in[1];  // [512][32]
    const float* weight      = (const float*)d_in[2];  // [32][16]
    const int*   edge_src    = (const int*)d_in[3];    // edge_index[0][:]
    const int*   range_list  = (const int*)d_in[4];    // [4096][2]
    const float* x_norm      = (const float*)d_in[5];  // [100000]

    float*  out = (float*)d_out;
    ushort* Mt  = (ushort*)d_ws;                        // 16 KB bf16 [16][512]
    ushort* y   = (ushort*)((char*)d_ws + 16384);       // 3.2 MB bf16

    k_embed_weight<<<32, 256, 0, stream>>>(embed, weight, Mt);

    int nblk = (NTILES + 3) / 4;                        // 1563
    k_gemm_y<<<nblk, 256, 81920, stream>>>(source_feat, x_norm, Mt, y);

    k_gather_mean<<<N_TARGET, 256, 0, stream>>>(y, edge_src, range_list, out);
}